// Round 1
// baseline (279.824 us; speedup 1.0000x reference)
//
#include <hip/hip_runtime.h>
#include <cstdint>

#define BB 256
#define DD 512
#define CC 345
#define NBANK 50000
#define NPAD 50048          // 782 * 64
#define KNEI 5
#define ALPHAC 1.0f
#define EPSN 1e-12f
#define NHALF 782           // 64-col tiles = one per block
#define CSLOTS (NHALF * 2)  // 2 keys per tile -> 1564 u64 per row

typedef short short8 __attribute__((ext_vector_type(8)));
typedef float f32x4 __attribute__((ext_vector_type(4)));
typedef unsigned long long u64;

__device__ inline uint32_t f2bf1(float x) {
    union { float f; uint32_t u; } v; v.f = x;
    return (v.u + 0x7FFFu + ((v.u >> 16) & 1u)) >> 16;
}
__device__ inline uint32_t pack2(float a, float b) {
    return f2bf1(a) | (f2bf1(b) << 16);
}
__device__ inline float bl(uint32_t x) {
    union { uint32_t u; float f; } v; v.u = x << 16; return v.f;
}
__device__ inline float bh(uint32_t x) {
    union { uint32_t u; float f; } v; v.u = x & 0xFFFF0000u; return v.f;
}
// packed sort key: high32 = monotone float bits, low32 = ~j (bigger = better)
__device__ inline u64 mkkey(float v, int j) {
    union { float f; uint32_t u; } c; c.f = v;
    uint32_t b = c.u;
    uint32_t k = (b & 0x80000000u) ? ~b : (b | 0x80000000u);
    return ((u64)k << 32) | (uint32_t)(~j);
}
__device__ inline u64 umax64(u64 a, u64 b) { return a > b ? a : b; }
__device__ inline u64 shfl_xor_u64(u64 v, int m) {
    int lo = __shfl_xor((int)(uint32_t)v, m, 64);
    int hi = __shfl_xor((int)(v >> 32), m, 64);
    return ((u64)(uint32_t)hi << 32) | (uint32_t)lo;
}
__device__ inline void ins6u(u64 k, u64* lv) {
    if (k > lv[5]) {
        int q = 5;
        while (q > 0 && k > lv[q - 1]) { lv[q] = lv[q - 1]; q--; }
        lv[q] = k;
    }
}
// 256-thread LDS tree merge of per-thread sorted-desc 6-tuples -> sv[0..5]
__device__ inline void tree6u(u64* sv, int t, const u64* lv) {
#pragma unroll
    for (int r = 0; r < 6; r++) sv[t * 6 + r] = lv[r];
    __syncthreads();
    for (int s = 128; s > 0; s >>= 1) {
        if (t < s) {
            u64 av[6], bv[6], rv[6];
#pragma unroll
            for (int r = 0; r < 6; r++) { av[r] = sv[t * 6 + r]; bv[r] = sv[(t + s) * 6 + r]; }
            int x = 0, y = 0;
#pragma unroll
            for (int o = 0; o < 6; o++) {
                bool pk = av[x] > bv[y];
                rv[o] = pk ? av[x] : bv[y];
                x += pk; y += !pk;
            }
#pragma unroll
            for (int r = 0; r < 6; r++) sv[t * 6 + r] = rv[r];
        }
        __syncthreads();
    }
}
// async 16B/lane global->LDS: gptr per-lane, lptr wave-uniform
__device__ inline void async16(const void* g, void* l) {
    __builtin_amdgcn_global_load_lds(
        (const __attribute__((address_space(1))) unsigned int*)g,
        (__attribute__((address_space(3))) unsigned int*)l, 16, 0, 0);
}
// swizzled tiled offset (elements): 128-row x 64-col tile, row r, 8-el chunk ch
__device__ inline size_t sw_off(int tile, int r, int ch) {
    return (size_t)tile * 8192 + r * 64 + ((ch ^ (r & 7)) * 8);
}

// Kernel 1: repl[j] = -1
__global__ void repl_init_kernel(int* __restrict__ repl) {
    int idx = blockIdx.x * 256 + threadIdx.x;
    if (idx < NPAD) repl[idx] = -1;
}

// Kernel 2: zero out; last-write-wins scatter repl[trg[b]] = b
__global__ void winner_kernel(const int* __restrict__ trg, int* __restrict__ repl,
                              float* __restrict__ out) {
    int t = threadIdx.x;
    __shared__ int st[BB];
    if (t == 0) out[0] = 0.f;
    st[t] = trg[t];
    __syncthreads();
    int mv = st[t];
    int w = 1;
    for (int b2 = t + 1; b2 < BB; b2++)
        if (st[b2] == mv) w = 0;
    if (w) repl[mv] = t;
}

// Kernel 3: fused row L2-normalize (-> fnb plain + fnb2 swizzled) + row softmax
__global__ void norm_softmax_kernel(const float* __restrict__ feat,
                                    const float* __restrict__ pred,
                                    unsigned short* __restrict__ fnb,
                                    unsigned short* __restrict__ fnb2,
                                    float* __restrict__ p) {
    int b = blockIdx.x, t = threadIdx.x;
    __shared__ float red[256];
    float x0 = feat[b * DD + t];
    float x1 = feat[b * DD + t + 256];
    red[t] = x0 * x0 + x1 * x1;
    __syncthreads();
    for (int s = 128; s > 0; s >>= 1) {
        if (t < s) red[t] += red[t + s];
        __syncthreads();
    }
    float inv = 1.0f / fmaxf(sqrtf(red[0]), EPSN);
    if (t < 64) {
        const f32x4* src = (const f32x4*)(feat + b * DD + t * 8);
        f32x4 f0 = src[0], f1 = src[1];
        uint4 u = make_uint4(pack2(f0[0] * inv, f0[1] * inv),
                             pack2(f0[2] * inv, f0[3] * inv),
                             pack2(f1[0] * inv, f1[1] * inv),
                             pack2(f1[2] * inv, f1[3] * inv));
        *(uint4*)(fnb + b * DD + t * 8) = u;
        int mtile = b >> 7, r = b & 127, kt = t >> 3, ch = t & 7;
        *(uint4*)(fnb2 + sw_off(mtile * 8 + kt, r, ch)) = u;
    }
    __syncthreads();
    float y0 = (t < CC) ? pred[b * CC + t] : -3.0e38f;
    float y1 = (t + 256 < CC) ? pred[b * CC + t + 256] : -3.0e38f;
    red[t] = fmaxf(y0, y1);
    __syncthreads();
    for (int s = 128; s > 0; s >>= 1) {
        if (t < s) red[t] = fmaxf(red[t], red[t + s]);
        __syncthreads();
    }
    float M = red[0];
    __syncthreads();
    float e0 = (t < CC) ? expf(y0 - M) : 0.f;
    float e1 = (t + 256 < CC) ? expf(y1 - M) : 0.f;
    red[t] = e0 + e1;
    __syncthreads();
    for (int s = 128; s > 0; s >>= 1) {
        if (t < s) red[t] += red[t + s];
        __syncthreads();
    }
    float si = 1.0f / red[0];
    if (t < CC) p[b * CC + t] = e0 * si;
    if (t + 256 < CC) p[b * CC + t + 256] = e1 * si;
}

// Kernel 4: 256x64x512 bf16 MFMA GEMM with FUSED f32->bf16 bank conversion and
// repl scatter patch in B staging; branchless per-(row,tile) top-2 key epilogue.
// Each block owns 64 bank rows exclusively -> bank is fetched from HBM once.
//
// v2: 2-phase double-buffered pipeline (guide T3 minimum form + T14 split):
//   - LDS doubled to 2 x (32KB A + 8KB B) = 80 KB (2 blocks/CU; grid gives ~3,
//     measured residency was only ~1.7-2 anyway, so no occupancy loss).
//   - At top of iteration kt: issue kt+1 B global loads (to regs) and kt+1 A
//     global_load_lds asyncs into buf[nxt]; both have the whole kt compute
//     phase (~400 cyc of ds_read+MFMA) to cover their latency.
//   - f32->bf16 convert + swizzled ds_write of B happens AFTER the MFMAs
//     (issue-early / write-late), so the vmcnt wait on the B regs lands after
//     the compute instead of stalling before it.
//   - One barrier per K-step (its vmcnt(0) drain now hits mostly-landed loads).
__global__ __launch_bounds__(256) void gemm_topk_kernel(
        const unsigned short* __restrict__ fnb2, const float* __restrict__ bank,
        const unsigned short* __restrict__ fnb, const int* __restrict__ repl,
        u64* __restrict__ cand) {
    __shared__ __align__(16) char smem[2][40960];

    int t = threadIdx.x;
    int ntb = blockIdx.x;          // 0..781
    int j0 = ntb * 64;
    int w = t >> 6, lane = t & 63, quad = lane >> 4, l16 = lane & 15;

    // B staging role: 4 threads per bank row, 16 floats each
    int br = t >> 2, cq = t & 3;
    int bj = j0 + br;
    int rp = (bj < NBANK) ? repl[bj] : -2;   // -2 OOB, -1 bank row, >=0 fnb row
    // per-thread source cursors (constant across kt; kt adds a static offset)
    const uint4* fsrc = (const uint4*)(fnb + (size_t)((rp >= 0) ? rp : 0) * DD) + cq * 2;
    const f32x4* bsrc = (const f32x4*)(bank + (size_t)bj * DD) + cq * 4;
    const char* fnb2b = (const char*)fnb2;

    f32x4 acc[4][4];
#pragma unroll
    for (int mt = 0; mt < 4; mt++)
#pragma unroll
        for (int nt = 0; nt < 4; nt++)
            acc[mt][nt] = (f32x4){0.f, 0.f, 0.f, 0.f};

    // in-flight B registers for the next K-tile
    uint4 pb0, pb1;
    f32x4 pf0, pf1, pf2, pf3;

    // ---------------- prologue: stage kt=0 into buf 0 ----------------
    if (rp >= 0)       { pb0 = fsrc[0]; pb1 = fsrc[1]; }
    else if (rp == -1) { pf0 = bsrc[0]; pf1 = bsrc[1]; pf2 = bsrc[2]; pf3 = bsrc[3]; }
    {
        const char* asrc = fnb2b + (size_t)((w < 2 ? 0 : 8) * 16384 + (w & 1) * 8192);
        char* adst = smem[0] + w * 8192;
#pragma unroll
        for (int u = 0; u < 8; u++)
            async16(asrc + u * 1024 + lane * 16, adst + u * 1024);
    }
    {
        uint4 b0, b1;
        if (rp >= 0)       { b0 = pb0; b1 = pb1; }
        else if (rp == -1) {
            b0 = make_uint4(pack2(pf0[0], pf0[1]), pack2(pf0[2], pf0[3]),
                            pack2(pf1[0], pf1[1]), pack2(pf1[2], pf1[3]));
            b1 = make_uint4(pack2(pf2[0], pf2[1]), pack2(pf2[2], pf2[3]),
                            pack2(pf3[0], pf3[1]), pack2(pf3[2], pf3[3]));
        } else { b0 = make_uint4(0, 0, 0, 0); b1 = make_uint4(0, 0, 0, 0); }
        unsigned short* Bs0 = (unsigned short*)(smem[0] + 32768);
        int c0 = cq * 2;
        *(uint4*)(Bs0 + br * 64 + ((c0 ^ (br & 7)) * 8)) = b0;
        *(uint4*)(Bs0 + br * 64 + (((c0 + 1) ^ (br & 7)) * 8)) = b1;
    }
    __syncthreads();

    // ---------------- 2-phase main loop ----------------
    for (int kt = 0; kt < 8; kt++) {
        int cur = kt & 1;
        int nxt = cur ^ 1;
        if (kt < 7) {
            // issue next-tile loads: B -> regs, A -> async global_load_lds
            if (rp >= 0)       { pb0 = fsrc[(kt + 1) * 8];  pb1 = fsrc[(kt + 1) * 8 + 1]; }
            else if (rp == -1) { pf0 = bsrc[(kt + 1) * 16];     pf1 = bsrc[(kt + 1) * 16 + 1];
                                 pf2 = bsrc[(kt + 1) * 16 + 2]; pf3 = bsrc[(kt + 1) * 16 + 3]; }
            const char* asrc = fnb2b +
                (size_t)((w < 2 ? kt + 1 : kt + 9) * 16384 + (w & 1) * 8192);
            char* adst = smem[nxt] + w * 8192;
#pragma unroll
            for (int u = 0; u < 8; u++)
                async16(asrc + u * 1024 + lane * 16, adst + u * 1024);
        }
        // compute kt from buf[cur]
        unsigned short* As = (unsigned short*)smem[cur];
        unsigned short* Bs = (unsigned short*)(smem[cur] + 32768);
#pragma unroll
        for (int ks = 0; ks < 2; ks++) {
            int swz = ((ks * 4 + quad) ^ (l16 & 7)) * 8;
            short8 af[4], bf[4];
#pragma unroll
            for (int mt = 0; mt < 4; mt++)
                af[mt] = *(const short8*)(As + (w * 64 + mt * 16 + l16) * 64 + swz);
#pragma unroll
            for (int nt = 0; nt < 4; nt++)
                bf[nt] = *(const short8*)(Bs + (nt * 16 + l16) * 64 + swz);
#pragma unroll
            for (int mt = 0; mt < 4; mt++)
#pragma unroll
                for (int nt = 0; nt < 4; nt++)
                    acc[mt][nt] = __builtin_amdgcn_mfma_f32_16x16x32_bf16(
                        af[mt], bf[nt], acc[mt][nt], 0, 0, 0);
        }
        // write-late: convert + store next B tile after the MFMAs
        if (kt < 7) {
            uint4 b0, b1;
            if (rp >= 0)       { b0 = pb0; b1 = pb1; }
            else if (rp == -1) {
                b0 = make_uint4(pack2(pf0[0], pf0[1]), pack2(pf0[2], pf0[3]),
                                pack2(pf1[0], pf1[1]), pack2(pf1[2], pf1[3]));
                b1 = make_uint4(pack2(pf2[0], pf2[1]), pack2(pf2[2], pf2[3]),
                                pack2(pf3[0], pf3[1]), pack2(pf3[2], pf3[3]));
            } else { b0 = make_uint4(0, 0, 0, 0); b1 = make_uint4(0, 0, 0, 0); }
            unsigned short* Bn = (unsigned short*)(smem[nxt] + 32768);
            int c0 = cq * 2;
            *(uint4*)(Bn + br * 64 + ((c0 ^ (br & 7)) * 8)) = b0;
            *(uint4*)(Bn + br * 64 + (((c0 + 1) ^ (br & 7)) * 8)) = b1;
        }
        __syncthreads();
    }

    // Branchless epilogue: top-2 packed keys per (row, this block's 64 cols)
    bool maskPad[4];
#pragma unroll
    for (int nt = 0; nt < 4; nt++)
        maskPad[nt] = (ntb == NHALF - 1) && ((j0 + nt * 16 + l16) >= NBANK);

#pragma unroll
    for (int mt = 0; mt < 4; mt++)
#pragma unroll
        for (int r2 = 0; r2 < 4; r2++) {
            u64 k[4];
#pragma unroll
            for (int nt = 0; nt < 4; nt++) {
                int j = j0 + nt * 16 + l16;
                k[nt] = maskPad[nt] ? 0ull : mkkey(acc[mt][nt][r2], j);
            }
            u64 m = umax64(umax64(k[0], k[1]), umax64(k[2], k[3]));
#pragma unroll
            for (int off = 1; off < 16; off <<= 1)
                m = umax64(m, shfl_xor_u64(m, off));
            u64 top1 = m;
#pragma unroll
            for (int nt = 0; nt < 4; nt++) k[nt] = (k[nt] == top1) ? 0ull : k[nt];
            m = umax64(umax64(k[0], k[1]), umax64(k[2], k[3]));
#pragma unroll
            for (int off = 1; off < 16; off <<= 1)
                m = umax64(m, shfl_xor_u64(m, off));
            if (l16 == 0) {
                int gi = w * 64 + mt * 16 + quad * 4 + r2;
                u64* cp = cand + (size_t)gi * CSLOTS + ntb * 2;
                cp[0] = top1; cp[1] = m;
            }
        }
}

// Kernel 5: per-row merge of 1564 stored keys -> exact top-6 (fallback rescan
// of any tile whose stored 2nd >= merged 6th; ~never executes) -> ranks 1..5
__global__ __launch_bounds__(256) void merge_kernel(
        const u64* __restrict__ cand, const unsigned short* __restrict__ fnb,
        const float* __restrict__ bank, const int* __restrict__ repl,
        int* __restrict__ nidx) {
    int i = blockIdx.x, t = threadIdx.x;
    __shared__ u64 sv[1536];
    __shared__ uint32_t fm[25];
    __shared__ int fl[128];
    __shared__ int nf;
    __shared__ float a[512];
    const u64* cr = cand + (size_t)i * CSLOTS;

    u64 lv[6] = {0, 0, 0, 0, 0, 0};
    for (int q = t; q < CSLOTS; q += 256) ins6u(cr[q], lv);
    if (t < 25) fm[t] = 0;
    if (t == 0) nf = 0;
    tree6u(sv, t, lv);
    u64 M6 = sv[5];
    __syncthreads();
    for (int h = t; h < NHALF; h += 256) {
        if (cr[h * 2 + 1] >= M6) {
            int s = atomicAdd(&nf, 1);
            if (s < 128) fl[s] = h;
            atomicOr(&fm[h >> 5], 1u << (h & 31));
        }
    }
    __syncthreads();
    if (nf > 0) {   // exact fallback — rare
        uint32_t wrd = ((const uint32_t*)(fnb + (size_t)i * DD))[t];
        a[2 * t] = bl(wrd);
        a[2 * t + 1] = bh(wrd);
        __syncthreads();
        u64 l2[6] = {0, 0, 0, 0, 0, 0};
        for (int q = t; q < CSLOTS; q += 256) {    // stored keys, unflagged tiles
            int h = q >> 1;
            if (!((fm[h >> 5] >> (h & 31)) & 1u)) ins6u(cr[q], l2);
        }
        int nfl = nf < 128 ? nf : 128;
        for (int s = 0; s < nfl; s++) {            // full recompute, flagged tiles
            int h = fl[s];
            if (t < 64) {
                int j = h * 64 + t;
                if (j < NBANK) {
                    int rp = repl[j];
                    float dot = 0.f;
                    if (rp >= 0) {
                        const uint32_t* rw = (const uint32_t*)(fnb + (size_t)rp * DD);
                        for (int kk = 0; kk < 256; kk++) {
                            uint32_t u = rw[kk];
                            dot += bl(u) * a[2 * kk] + bh(u) * a[2 * kk + 1];
                        }
                    } else {
                        const float* rw = bank + (size_t)j * DD;
                        for (int kk = 0; kk < DD; kk++)
                            dot += bl(f2bf1(rw[kk])) * a[kk];
                    }
                    ins6u(mkkey(dot, j), l2);
                }
            }
        }
        __syncthreads();
        tree6u(sv, t, l2);
    }
    if (t == 0) {
#pragma unroll
        for (int r = 1; r < 6; r++)
            nidx[i * KNEI + r - 1] = (int)(~(uint32_t)(sv[r] & 0xFFFFFFFFull));
    }
}

// Kernel 6: fused KL term (blocks 0..255) + neg_pred columns (blocks 256..600)
__global__ void kl_negpred_kernel(const float* __restrict__ p,
                                  const float* __restrict__ sbank,
                                  const int* __restrict__ nidx,
                                  const int* __restrict__ trg,
                                  float* __restrict__ out) {
    int bid = blockIdx.x, t = threadIdx.x;
    __shared__ float red[256];
    __shared__ float aux[256];
    if (bid < BB) {
        int b = bid;
        __shared__ int st[BB];
        __shared__ int sj[KNEI], sb[KNEI];
        st[t] = trg[t];
        __syncthreads();
        if (t < KNEI) {
            int j = nidx[b * KNEI + t];
            sj[t] = j;
            int src = -1;
            for (int b2 = 0; b2 < BB; b2++)
                if (st[b2] == j) src = b2;   // last wins
            sb[t] = src;
        }
        __syncthreads();
        float local = 0.f;
        for (int k = 0; k < KNEI; k++) {
            int j = sj[k], src = sb[k];
            const float* srow = (src >= 0) ? (p + src * CC) : (sbank + (size_t)j * CC);
            for (int c = t; c < CC; c += 256) {
                float s = srow[c];
                local += s * (logf(s) - p[b * CC + c]);
            }
        }
        red[t] = local;
        __syncthreads();
        for (int s = 128; s > 0; s >>= 1) {
            if (t < s) red[t] += red[t + s];
            __syncthreads();
        }
        if (t == 0) atomicAdd(out, red[0] * (1.0f / BB));
    } else {
        int c = bid - BB;
        float v = p[t * CC + c];
        red[t] = v;
        aux[t] = v * v;
        __syncthreads();
        for (int s = 128; s > 0; s >>= 1) {
            if (t < s) { red[t] += red[t + s]; aux[t] += aux[t + s]; }
            __syncthreads();
        }
        if (t == 0) atomicAdd(out, ALPHAC * (red[0] * red[0] - aux[0]) * (1.0f / BB));
    }
}

extern "C" void kernel_launch(void* const* d_in, const int* in_sizes, int n_in,
                              void* d_out, int out_size, void* d_ws, size_t ws_size,
                              hipStream_t stream) {
    const float* feat  = (const float*)d_in[0];
    const float* pred  = (const float*)d_in[1];
    const float* bank  = (const float*)d_in[2];
    const float* sbank = (const float*)d_in[3];
    const int*   trg   = (const int*)d_in[4];
    float* out = (float*)d_out;

    char* ws = (char*)d_ws;
    unsigned short* fnb2 = (unsigned short*)ws;              //   262,144 B
    unsigned short* fnb  = (unsigned short*)(ws + 262144);   //   262,144 B
    float*          p    = (float*)(ws + 524288);            //   353,280 B
    int*            repl = (int*)(ws + 877568);              //   200,192 B
    u64*            cand = (u64*)(ws + 1077760);             // 3,203,072 B
    int*            nidx = (int*)(ws + 4280832);             //     5,120 B

    repl_init_kernel<<<(NPAD + 255) / 256, 256, 0, stream>>>(repl);
    winner_kernel<<<1, 256, 0, stream>>>(trg, repl, out);
    norm_softmax_kernel<<<BB, 256, 0, stream>>>(feat, pred, fnb, fnb2, p);
    gemm_topk_kernel<<<NHALF, 256, 0, stream>>>(fnb2, bank, fnb, repl, cand);
    merge_kernel<<<BB, 256, 0, stream>>>(cand, fnb, bank, repl, nidx);
    kl_negpred_kernel<<<BB + CC, 256, 0, stream>>>(p, sbank, nidx, trg, out);
}

// Round 2
// 270.834 us; speedup vs baseline: 1.0332x; 1.0332x over previous
//
#include <hip/hip_runtime.h>
#include <cstdint>

#define BB 256
#define DD 512
#define CC 345
#define NBANK 50000
#define NPAD 50048          // 782 * 64
#define KNEI 5
#define ALPHAC 1.0f
#define EPSN 1e-12f
#define NHALF 782           // 64-col tiles
#define CSLOTS (NHALF * 2)  // 2 keys per tile -> 1564 u64 per row

typedef short short8 __attribute__((ext_vector_type(8)));
typedef float f32x4 __attribute__((ext_vector_type(4)));
typedef unsigned long long u64;

__device__ inline uint32_t f2bf1(float x) {
    union { float f; uint32_t u; } v; v.f = x;
    return (v.u + 0x7FFFu + ((v.u >> 16) & 1u)) >> 16;
}
__device__ inline uint32_t pack2(float a, float b) {
    return f2bf1(a) | (f2bf1(b) << 16);
}
__device__ inline float bl(uint32_t x) {
    union { uint32_t u; float f; } v; v.u = x << 16; return v.f;
}
__device__ inline float bh(uint32_t x) {
    union { uint32_t u; float f; } v; v.u = x & 0xFFFF0000u; return v.f;
}
// packed sort key: high32 = monotone float bits, low32 = ~j (bigger = better)
__device__ inline u64 mkkey(float v, int j) {
    union { float f; uint32_t u; } c; c.f = v;
    uint32_t b = c.u;
    uint32_t k = (b & 0x80000000u) ? ~b : (b | 0x80000000u);
    return ((u64)k << 32) | (uint32_t)(~j);
}
__device__ inline u64 umax64(u64 a, u64 b) { return a > b ? a : b; }
__device__ inline u64 shfl_xor_u64(u64 v, int m) {
    int lo = __shfl_xor((int)(uint32_t)v, m, 64);
    int hi = __shfl_xor((int)(v >> 32), m, 64);
    return ((u64)(uint32_t)hi << 32) | (uint32_t)lo;
}
__device__ inline void ins6u(u64 k, u64* lv) {
    if (k > lv[5]) {
        int q = 5;
        while (q > 0 && k > lv[q - 1]) { lv[q] = lv[q - 1]; q--; }
        lv[q] = k;
    }
}
// 256-thread LDS tree merge of per-thread sorted-desc 6-tuples -> sv[0..5]
__device__ inline void tree6u(u64* sv, int t, const u64* lv) {
#pragma unroll
    for (int r = 0; r < 6; r++) sv[t * 6 + r] = lv[r];
    __syncthreads();
    for (int s = 128; s > 0; s >>= 1) {
        if (t < s) {
            u64 av[6], bv[6], rv[6];
#pragma unroll
            for (int r = 0; r < 6; r++) { av[r] = sv[t * 6 + r]; bv[r] = sv[(t + s) * 6 + r]; }
            int x = 0, y = 0;
#pragma unroll
            for (int o = 0; o < 6; o++) {
                bool pk = av[x] > bv[y];
                rv[o] = pk ? av[x] : bv[y];
                x += pk; y += !pk;
            }
#pragma unroll
            for (int r = 0; r < 6; r++) sv[t * 6 + r] = rv[r];
        }
        __syncthreads();
    }
}
// async 16B/lane global->LDS: gptr per-lane, lptr wave-uniform
__device__ inline void async16(const void* g, void* l) {
    __builtin_amdgcn_global_load_lds(
        (const __attribute__((address_space(1))) unsigned int*)g,
        (__attribute__((address_space(3))) unsigned int*)l, 16, 0, 0);
}
// swizzled tiled offset (elements): 128-row x 64-col tile, row r, 8-el chunk ch
__device__ inline size_t sw_off(int tile, int r, int ch) {
    return (size_t)tile * 8192 + r * 64 + ((ch ^ (r & 7)) * 8);
}

// Kernel 1: repl[j] = -1
__global__ void repl_init_kernel(int* __restrict__ repl) {
    int idx = blockIdx.x * 256 + threadIdx.x;
    if (idx < NPAD) repl[idx] = -1;
}

// Kernel 2: zero out; last-write-wins scatter repl[trg[b]] = b
__global__ void winner_kernel(const int* __restrict__ trg, int* __restrict__ repl,
                              float* __restrict__ out) {
    int t = threadIdx.x;
    __shared__ int st[BB];
    if (t == 0) out[0] = 0.f;
    st[t] = trg[t];
    __syncthreads();
    int mv = st[t];
    int w = 1;
    for (int b2 = t + 1; b2 < BB; b2++)
        if (st[b2] == mv) w = 0;
    if (w) repl[mv] = t;
}

// Kernel 3: fused row L2-normalize (-> fnb plain + fnb2 swizzled) + row softmax
__global__ void norm_softmax_kernel(const float* __restrict__ feat,
                                    const float* __restrict__ pred,
                                    unsigned short* __restrict__ fnb,
                                    unsigned short* __restrict__ fnb2,
                                    float* __restrict__ p) {
    int b = blockIdx.x, t = threadIdx.x;
    __shared__ float red[256];
    float x0 = feat[b * DD + t];
    float x1 = feat[b * DD + t + 256];
    red[t] = x0 * x0 + x1 * x1;
    __syncthreads();
    for (int s = 128; s > 0; s >>= 1) {
        if (t < s) red[t] += red[t + s];
        __syncthreads();
    }
    float inv = 1.0f / fmaxf(sqrtf(red[0]), EPSN);
    if (t < 64) {
        const f32x4* src = (const f32x4*)(feat + b * DD + t * 8);
        f32x4 f0 = src[0], f1 = src[1];
        uint4 u = make_uint4(pack2(f0[0] * inv, f0[1] * inv),
                             pack2(f0[2] * inv, f0[3] * inv),
                             pack2(f1[0] * inv, f1[1] * inv),
                             pack2(f1[2] * inv, f1[3] * inv));
        *(uint4*)(fnb + b * DD + t * 8) = u;
        int mtile = b >> 7, r = b & 127, kt = t >> 3, ch = t & 7;
        *(uint4*)(fnb2 + sw_off(mtile * 8 + kt, r, ch)) = u;
    }
    __syncthreads();
    float y0 = (t < CC) ? pred[b * CC + t] : -3.0e38f;
    float y1 = (t + 256 < CC) ? pred[b * CC + t + 256] : -3.0e38f;
    red[t] = fmaxf(y0, y1);
    __syncthreads();
    for (int s = 128; s > 0; s >>= 1) {
        if (t < s) red[t] = fmaxf(red[t], red[t + s]);
        __syncthreads();
    }
    float M = red[0];
    __syncthreads();
    float e0 = (t < CC) ? expf(y0 - M) : 0.f;
    float e1 = (t + 256 < CC) ? expf(y1 - M) : 0.f;
    red[t] = e0 + e1;
    __syncthreads();
    for (int s = 128; s > 0; s >>= 1) {
        if (t < s) red[t] += red[t + s];
        __syncthreads();
    }
    float si = 1.0f / red[0];
    if (t < CC) p[b * CC + t] = e0 * si;
    if (t + 256 < CC) p[b * CC + t + 256] = e1 * si;
}

// Kernel 4: 128x64x512 bf16 MFMA GEMM with FUSED f32->bf16 bank conversion and
// repl scatter patch in B staging; branchless per-(row,tile) top-2 key epilogue.
//
// v3 (post-mortem of v2's regression): latency hiding on this problem comes
// from inter-block TLP, not intra-block pipelining (v2: 80KB LDS -> 2 blk/CU,
// occupancy 18%, 108us). So go the other way: HALVE the block (128 rows x 64
// cols), DOUBLE the grid (1564 blocks), single-buffer LDS = 16KB A + 8KB B =
// 24KB -> 6 blocks/CU LDS-capacity, acc[2][4] keeps VGPR low. ~6 resident
// K-loops per CU overlap each other's vmcnt(0)+barrier drains.
// B tiles are read by 2 blocks (one per row-half); bank fits L3 so the
// duplicate read is an Infinity-Cache hit, not extra HBM.
__global__ __launch_bounds__(256) void gemm_topk_kernel(
        const unsigned short* __restrict__ fnb2, const float* __restrict__ bank,
        const unsigned short* __restrict__ fnb, const int* __restrict__ repl,
        u64* __restrict__ cand) {
    __shared__ __align__(16) char smem[24576];
    unsigned short* As = (unsigned short*)smem;            // [128][64] 16 KB
    unsigned short* Bs = (unsigned short*)(smem + 16384);  // [64][64]   8 KB

    int t = threadIdx.x;
    int bid = blockIdx.x;
    int ntb = bid >> 1;            // 0..781 col tile
    int rh  = bid & 1;             // row half: rows rh*128 .. rh*128+127
    int j0 = ntb * 64;
    int w = t >> 6, lane = t & 63, quad = lane >> 4, l16 = lane & 15;

    // B staging role: 4 threads per bank row, 16 floats each
    int br = t >> 2, cq = t & 3;
    int bj = j0 + br;
    int rp = (bj < NBANK) ? repl[bj] : -2;   // -2 OOB, -1 bank row, >=0 fnb row

    f32x4 acc[2][4];
#pragma unroll
    for (int mt = 0; mt < 2; mt++)
#pragma unroll
        for (int nt = 0; nt < 4; nt++)
            acc[mt][nt] = (f32x4){0.f, 0.f, 0.f, 0.f};

    const char* fnb2b = (const char*)fnb2;

    for (int kt = 0; kt < 8; kt++) {
        // A: async16 from swizzled fnb2 tile (rh*8+kt); wave w copies 4 KB
        // (rows w*32 .. w*32+31 of the 128-row tile)
        const char* asrc = fnb2b + (size_t)((rh * 8 + kt) * 16384 + w * 4096);
        char* adst = smem + w * 4096;
#pragma unroll
        for (int u = 0; u < 4; u++)
            async16(asrc + u * 1024 + lane * 16, adst + u * 1024);
        // B: f32 bank -> registers -> bf16 -> swizzled LDS (repl-patched)
        {
            uint4 b0, b1;
            if (rp >= 0) {
                const uint4* s = (const uint4*)(fnb + (size_t)rp * DD + kt * 64 + cq * 16);
                b0 = s[0]; b1 = s[1];
            } else if (rp == -1) {
                const f32x4* s = (const f32x4*)(bank + (size_t)bj * DD + kt * 64 + cq * 16);
                f32x4 f0 = s[0], f1 = s[1], f2 = s[2], f3 = s[3];
                b0 = make_uint4(pack2(f0[0], f0[1]), pack2(f0[2], f0[3]),
                                pack2(f1[0], f1[1]), pack2(f1[2], f1[3]));
                b1 = make_uint4(pack2(f2[0], f2[1]), pack2(f2[2], f2[3]),
                                pack2(f3[0], f3[1]), pack2(f3[2], f3[3]));
            } else {
                b0 = make_uint4(0, 0, 0, 0);
                b1 = make_uint4(0, 0, 0, 0);
            }
            int c0 = cq * 2;
            *(uint4*)(Bs + br * 64 + ((c0 ^ (br & 7)) * 8)) = b0;
            *(uint4*)(Bs + br * 64 + (((c0 + 1) ^ (br & 7)) * 8)) = b1;
        }
        __syncthreads();
#pragma unroll
        for (int ks = 0; ks < 2; ks++) {
            int swz = ((ks * 4 + quad) ^ (l16 & 7)) * 8;
            short8 af[2], bf[4];
#pragma unroll
            for (int mt = 0; mt < 2; mt++)
                af[mt] = *(const short8*)(As + (w * 32 + mt * 16 + l16) * 64 + swz);
#pragma unroll
            for (int nt = 0; nt < 4; nt++)
                bf[nt] = *(const short8*)(Bs + (nt * 16 + l16) * 64 + swz);
#pragma unroll
            for (int mt = 0; mt < 2; mt++)
#pragma unroll
                for (int nt = 0; nt < 4; nt++)
                    acc[mt][nt] = __builtin_amdgcn_mfma_f32_16x16x32_bf16(
                        af[mt], bf[nt], acc[mt][nt], 0, 0, 0);
        }
        __syncthreads();
    }

    // Branchless epilogue: top-2 packed keys per (row, this block's 64 cols)
    bool maskPad[4];
#pragma unroll
    for (int nt = 0; nt < 4; nt++)
        maskPad[nt] = (ntb == NHALF - 1) && ((j0 + nt * 16 + l16) >= NBANK);

#pragma unroll
    for (int mt = 0; mt < 2; mt++)
#pragma unroll
        for (int r2 = 0; r2 < 4; r2++) {
            u64 k[4];
#pragma unroll
            for (int nt = 0; nt < 4; nt++) {
                int j = j0 + nt * 16 + l16;
                k[nt] = maskPad[nt] ? 0ull : mkkey(acc[mt][nt][r2], j);
            }
            u64 m = umax64(umax64(k[0], k[1]), umax64(k[2], k[3]));
#pragma unroll
            for (int off = 1; off < 16; off <<= 1)
                m = umax64(m, shfl_xor_u64(m, off));
            u64 top1 = m;
#pragma unroll
            for (int nt = 0; nt < 4; nt++) k[nt] = (k[nt] == top1) ? 0ull : k[nt];
            m = umax64(umax64(k[0], k[1]), umax64(k[2], k[3]));
#pragma unroll
            for (int off = 1; off < 16; off <<= 1)
                m = umax64(m, shfl_xor_u64(m, off));
            if (l16 == 0) {
                int gi = rh * 128 + w * 32 + mt * 16 + quad * 4 + r2;
                u64* cp = cand + (size_t)gi * CSLOTS + ntb * 2;
                cp[0] = top1; cp[1] = m;
            }
        }
}

// Kernel 5: per-row merge of 1564 stored keys -> exact top-6 (fallback rescan
// of any tile whose stored 2nd >= merged 6th; ~never executes) -> ranks 1..5
__global__ __launch_bounds__(256) void merge_kernel(
        const u64* __restrict__ cand, const unsigned short* __restrict__ fnb,
        const float* __restrict__ bank, const int* __restrict__ repl,
        int* __restrict__ nidx) {
    int i = blockIdx.x, t = threadIdx.x;
    __shared__ u64 sv[1536];
    __shared__ uint32_t fm[25];
    __shared__ int fl[128];
    __shared__ int nf;
    __shared__ float a[512];
    const u64* cr = cand + (size_t)i * CSLOTS;

    u64 lv[6] = {0, 0, 0, 0, 0, 0};
    for (int q = t; q < CSLOTS; q += 256) ins6u(cr[q], lv);
    if (t < 25) fm[t] = 0;
    if (t == 0) nf = 0;
    tree6u(sv, t, lv);
    u64 M6 = sv[5];
    __syncthreads();
    for (int h = t; h < NHALF; h += 256) {
        if (cr[h * 2 + 1] >= M6) {
            int s = atomicAdd(&nf, 1);
            if (s < 128) fl[s] = h;
            atomicOr(&fm[h >> 5], 1u << (h & 31));
        }
    }
    __syncthreads();
    if (nf > 0) {   // exact fallback — rare
        uint32_t wrd = ((const uint32_t*)(fnb + (size_t)i * DD))[t];
        a[2 * t] = bl(wrd);
        a[2 * t + 1] = bh(wrd);
        __syncthreads();
        u64 l2[6] = {0, 0, 0, 0, 0, 0};
        for (int q = t; q < CSLOTS; q += 256) {    // stored keys, unflagged tiles
            int h = q >> 1;
            if (!((fm[h >> 5] >> (h & 31)) & 1u)) ins6u(cr[q], l2);
        }
        int nfl = nf < 128 ? nf : 128;
        for (int s = 0; s < nfl; s++) {            // full recompute, flagged tiles
            int h = fl[s];
            if (t < 64) {
                int j = h * 64 + t;
                if (j < NBANK) {
                    int rp = repl[j];
                    float dot = 0.f;
                    if (rp >= 0) {
                        const uint32_t* rw = (const uint32_t*)(fnb + (size_t)rp * DD);
                        for (int kk = 0; kk < 256; kk++) {
                            uint32_t u = rw[kk];
                            dot += bl(u) * a[2 * kk] + bh(u) * a[2 * kk + 1];
                        }
                    } else {
                        const float* rw = bank + (size_t)j * DD;
                        for (int kk = 0; kk < DD; kk++)
                            dot += bl(f2bf1(rw[kk])) * a[kk];
                    }
                    ins6u(mkkey(dot, j), l2);
                }
            }
        }
        __syncthreads();
        tree6u(sv, t, l2);
    }
    if (t == 0) {
#pragma unroll
        for (int r = 1; r < 6; r++)
            nidx[i * KNEI + r - 1] = (int)(~(uint32_t)(sv[r] & 0xFFFFFFFFull));
    }
}

// Kernel 6: fused KL term (blocks 0..255) + neg_pred columns (blocks 256..600)
__global__ void kl_negpred_kernel(const float* __restrict__ p,
                                  const float* __restrict__ sbank,
                                  const int* __restrict__ nidx,
                                  const int* __restrict__ trg,
                                  float* __restrict__ out) {
    int bid = blockIdx.x, t = threadIdx.x;
    __shared__ float red[256];
    __shared__ float aux[256];
    if (bid < BB) {
        int b = bid;
        __shared__ int st[BB];
        __shared__ int sj[KNEI], sb[KNEI];
        st[t] = trg[t];
        __syncthreads();
        if (t < KNEI) {
            int j = nidx[b * KNEI + t];
            sj[t] = j;
            int src = -1;
            for (int b2 = 0; b2 < BB; b2++)
                if (st[b2] == j) src = b2;   // last wins
            sb[t] = src;
        }
        __syncthreads();
        float local = 0.f;
        for (int k = 0; k < KNEI; k++) {
            int j = sj[k], src = sb[k];
            const float* srow = (src >= 0) ? (p + src * CC) : (sbank + (size_t)j * CC);
            for (int c = t; c < CC; c += 256) {
                float s = srow[c];
                local += s * (logf(s) - p[b * CC + c]);
            }
        }
        red[t] = local;
        __syncthreads();
        for (int s = 128; s > 0; s >>= 1) {
            if (t < s) red[t] += red[t + s];
            __syncthreads();
        }
        if (t == 0) atomicAdd(out, red[0] * (1.0f / BB));
    } else {
        int c = bid - BB;
        float v = p[t * CC + c];
        red[t] = v;
        aux[t] = v * v;
        __syncthreads();
        for (int s = 128; s > 0; s >>= 1) {
            if (t < s) { red[t] += red[t + s]; aux[t] += aux[t + s]; }
            __syncthreads();
        }
        if (t == 0) atomicAdd(out, ALPHAC * (red[0] * red[0] - aux[0]) * (1.0f / BB));
    }
}

extern "C" void kernel_launch(void* const* d_in, const int* in_sizes, int n_in,
                              void* d_out, int out_size, void* d_ws, size_t ws_size,
                              hipStream_t stream) {
    const float* feat  = (const float*)d_in[0];
    const float* pred  = (const float*)d_in[1];
    const float* bank  = (const float*)d_in[2];
    const float* sbank = (const float*)d_in[3];
    const int*   trg   = (const int*)d_in[4];
    float* out = (float*)d_out;

    char* ws = (char*)d_ws;
    unsigned short* fnb2 = (unsigned short*)ws;              //   262,144 B
    unsigned short* fnb  = (unsigned short*)(ws + 262144);   //   262,144 B
    float*          p    = (float*)(ws + 524288);            //   353,280 B
    int*            repl = (int*)(ws + 877568);              //   200,192 B
    u64*            cand = (u64*)(ws + 1077760);             // 3,203,072 B
    int*            nidx = (int*)(ws + 4280832);             //     5,120 B

    repl_init_kernel<<<(NPAD + 255) / 256, 256, 0, stream>>>(repl);
    winner_kernel<<<1, 256, 0, stream>>>(trg, repl, out);
    norm_softmax_kernel<<<BB, 256, 0, stream>>>(feat, pred, fnb, fnb2, p);
    gemm_topk_kernel<<<NHALF * 2, 256, 0, stream>>>(fnb2, bank, fnb, repl, cand);
    merge_kernel<<<BB, 256, 0, stream>>>(cand, fnb, bank, repl, nidx);
    kl_negpred_kernel<<<BB + CC, 256, 0, stream>>>(p, sbank, nidx, trg, out);
}